// Round 3
// baseline (1020.834 us; speedup 1.0000x reference)
//
#include <hip/hip_runtime.h>
#include <cstdint>
#include <cstddef>
#include <math.h>

#define S_TOT 4000
#define NY 30
#define ND 365
#define T_TOT (NY * ND)  // 10950
#define NBLK ((S_TOT / 8) * NY)  // 15000 stats blocks

__device__ __forceinline__ float pinf() { return __uint_as_float(0x7F800000u); }

// Monotone bijection: uint key -> float (total order), inverse of
// f2key(bits) = (bits & 0x80000000) ? ~bits : (bits | 0x80000000)
__device__ inline float key2f(unsigned k) {
    unsigned bits = (k & 0x80000000u) ? (k ^ 0x80000000u) : ~k;
    return __uint_as_float(bits);
}

// count of elements <= p across the wave's 6-reg value set (pads are +inf)
__device__ __forceinline__ int wcount(const float* v, float p) {
    int c = 0;
#pragma unroll
    for (int i = 0; i < 6; i++) c += (int)__popcll(__ballot(v[i] <= p));
    return c;
}

// Exact (need)-th smallest (1-based) of the wave's 365 values.
// Preconditions: cLo = wcount(v, lo) < need; wcount(v, hi) == 365 >= need.
// False-position bracketing (midpoint every other step) + exact finisher.
// Guaranteed-exact fallback to 32-iter key bisection for pathological data.
__device__ float select_rank(const float* v, int need, float lo, int cLo, float hi) {
    int cHi = 365;
    for (int it = 0; it < 24 && (cHi - cLo) > 2; ++it) {
        float mid;
        if (it & 1) {
            mid = lo + 0.5f * (hi - lo);
        } else {
            float t = (float)(need - cLo) * __frcp_rn((float)(cHi - cLo));
            mid = fmaf(t, hi - lo, lo);
        }
        if (!(mid > lo && mid < hi)) mid = lo + 0.5f * (hi - lo);
        if (!(mid > lo && mid < hi)) break;  // adjacent floats
        int c = wcount(v, mid);
        if (c >= need) { hi = mid; cHi = c; } else { lo = mid; cLo = c; }
    }
    if (cHi - cLo > 16) {
        // pathological (tie clusters / stagnation): exact bounded bisection
        unsigned klo = 0u, khi = 0xFFFFFFFFu;
        for (int it = 0; it < 32; ++it) {
            unsigned kmid = klo + ((khi - klo) >> 1);
            int c = wcount(v, key2f(kmid));
            if (c >= need) khi = kmid; else klo = kmid + 1;
        }
        return key2f(klo);
    }
    // finisher: r-th smallest among {x > lo}, r = need - cLo in [1,16]
    int r = need - cLo;
    float m[6];
#pragma unroll
    for (int i = 0; i < 6; i++) m[i] = (v[i] > lo) ? v[i] : pinf();
    float ans = 0.f;
    for (int e = 0; e < r; ++e) {
        float cur = m[0];
#pragma unroll
        for (int i = 1; i < 6; i++) cur = fminf(cur, m[i]);
#pragma unroll
        for (int off = 32; off; off >>= 1) cur = fminf(cur, __shfl_xor(cur, off, 64));
        ans = cur;
        if (e + 1 < r) {  // remove exactly one instance of cur (tie-safe)
            bool has = (m[0] == cur) | (m[1] == cur) | (m[2] == cur) |
                       (m[3] == cur) | (m[4] == cur) | (m[5] == cur);
            unsigned long long bal = __ballot(has);
            int leader = __ffsll((long long)bal) - 1;
            if ((int)(threadIdx.x & 63) == leader) {
                if (m[0] == cur) m[0] = pinf();
                else if (m[1] == cur) m[1] = pinf();
                else if (m[2] == cur) m[2] = pinf();
                else if (m[3] == cur) m[3] = pinf();
                else if (m[4] == cur) m[4] = pinf();
                else m[5] = pinf();
            }
        }
    }
    return ans;
}

// ---------------------------------------------------------------------------
// Kernel 0: zero the f64 accumulator (avoids hipMemsetAsync in capture path)
// ---------------------------------------------------------------------------
__global__ void zero_kernel(double* acc) { acc[0] = 0.0; }

// ---------------------------------------------------------------------------
// Kernel 1: per-(series, year) mean + 5 exact order statistics for BOTH
// arrays, PLUS fused RMSE partial sum (touches every input byte exactly once).
// One wave per (series, year); block = 8 waves = 8 series x 1 year.
// stats layout: stats[k][s][y], k: 0=meanP, 1..5=qP (ranks 364,357,182,109,7),
//                               6=meanT, 7..11=qT
// blockIdx remapped so each XCD owns a contiguous work range (64B-line halves
// shared by neighboring series-groups stay within one XCD's L2).
// ---------------------------------------------------------------------------
__global__ __launch_bounds__(512) void stats_kernel(const float* __restrict__ pred,
                                                    const float* __restrict__ targ,
                                                    float* __restrict__ stats,
                                                    double* __restrict__ acc) {
    const int b = blockIdx.x;
    const int work = (b & 7) * (NBLK / 8) + (b >> 3);  // bijective, 15000%8==0
    const int y = work % NY;
    const int s0 = (work / NY) * 8;

    __shared__ float ldsA[ND * 9];  // [day][series(8)+pad]
    __shared__ float ldsB[ND * 9];
    __shared__ double wred[8];

    const int tid = threadIdx.x;
    const size_t base = (size_t)y * ND * S_TOT + s0;

    double rs = 0.0;  // fused RMSE partial
    for (int idx = tid; idx < ND * 8; idx += 512) {
        int d = idx >> 3, c = idx & 7;
        size_t g = base + (size_t)d * S_TOT + c;
        float pv = pred[g], tv = targ[g];
        ldsA[d * 9 + c] = pv;
        ldsB[d * 9 + c] = tv;
        float df = pv - tv;
        rs += (double)df * df;
    }
#pragma unroll
    for (int off = 32; off; off >>= 1) rs += __shfl_xor(rs, off, 64);
    const int w = tid >> 6;
    const int lane = tid & 63;
    if (lane == 0) wred[w] = rs;
    __syncthreads();  // covers LDS staging AND wred
    if (tid == 0) {
        double t = 0.0;
#pragma unroll
        for (int i = 0; i < 8; i++) t += wred[i];
        atomicAdd(acc, t);
    }

    const int s = s0 + w;
    const float PINF = pinf();

    for (int arr = 0; arr < 2; ++arr) {
        const float* lds = arr ? ldsB : ldsA;
        float v[6];
#pragma unroll
        for (int i = 0; i < 6; i++) {
            int d = i * 64 + lane;
            v[i] = (d < ND) ? lds[d * 9 + w] : PINF;  // pads sort above all data
        }
        // mean (pads excluded)
        float sm = 0.f;
#pragma unroll
        for (int i = 0; i < 6; i++) {
            int d = i * 64 + lane;
            sm += (d < ND) ? v[i] : 0.f;
        }
#pragma unroll
        for (int off = 32; off; off >>= 1) sm += __shfl_xor(sm, off, 64);
        float mean = sm / 365.f;
        // max = rank 364 (exclude +inf pads)
        float mx = -PINF;
#pragma unroll
        for (int i = 0; i < 6; i++) {
            int d = i * 64 + lane;
            if (d < ND) mx = fmaxf(mx, v[i]);
        }
#pragma unroll
        for (int off = 32; off; off >>= 1) mx = fmaxf(mx, __shfl_xor(mx, off, 64));
        // min (pads +inf don't affect)
        float mn = v[0];
#pragma unroll
        for (int i = 1; i < 6; i++) mn = fminf(mn, v[i]);
#pragma unroll
        for (int off = 32; off; off >>= 1) mn = fminf(mn, __shfl_xor(mn, off, 64));
        const int cMn = wcount(v, mn);  // >= 1 (tie count of the minimum)

        // exact ranks {357,182,109,7} -> 1-based needs {358,183,110,8}
        float q98 = (cMn >= 358) ? mn : select_rank(v, 358, mn, cMn, mx);
        float q50 = (cMn >= 183) ? mn : select_rank(v, 183, mn, cMn, mx);
        float q30 = (cMn >= 110) ? mn : select_rank(v, 110, mn, cMn, mx);
        float q2  = (cMn >=   8) ? mn : select_rank(v,   8, mn, cMn, mx);

        float res[6] = {mean, mx, q98, q50, q30, q2};
        if (lane == 0) {
            const int kb = arr ? 6 : 0;
#pragma unroll
            for (int k = 0; k < 6; k++)
                stats[((size_t)(kb + k) * S_TOT + s) * NY + y] = res[k];
        }
    }
}

// ---------------------------------------------------------------------------
// Kernel 2: Theil-Sen median slope per (k, s). One wave per task.
// 435 pairwise slopes distributed 7/lane (pad +inf), median = rank 217
// (need 218). Safe 32-iter key bisection (this kernel is ~20 us, not worth
// complexity).
// ---------------------------------------------------------------------------
__global__ __launch_bounds__(256) void theilsen_kernel(const float* __restrict__ stats,
                                                       float* __restrict__ med) {
    const int task = blockIdx.x * 4 + (threadIdx.x >> 6);  // 48000 tasks
    const int lane = threadIdx.x & 63;
    const int k = task / S_TOT;
    const int s = task - k * S_TOT;
    const float* x = stats + ((size_t)k * S_TOT + s) * NY;
    const float PINF = pinf();
    float sl[7];
#pragma unroll
    for (int t = 0; t < 7; t++) {
        int p = t * 64 + lane;
        if (p < 435) {
            int i = 0, rem = p;
            while (rem >= 29 - i) { rem -= 29 - i; ++i; }
            int j = i + 1 + rem;
            sl[t] = (x[j] - x[i]) / (float)(j - i);
        } else {
            sl[t] = PINF;
        }
    }
    unsigned lo = 0u, hi = 0xFFFFFFFFu;
    for (int it = 0; it < 32; ++it) {
        unsigned mid = lo + ((hi - lo) >> 1);
        float pf = key2f(mid);
        int c = 0;
#pragma unroll
        for (int t = 0; t < 7; t++) c += (int)__popcll(__ballot(sl[t] <= pf));
        if (c >= 218) hi = mid; else lo = mid + 1;
    }
    if (lane == 0) med[task] = key2f(lo);
}

// ---------------------------------------------------------------------------
// Kernel 3: final combine (single block)
// ---------------------------------------------------------------------------
__global__ __launch_bounds__(1024) void final_kernel(const float* __restrict__ med,
                                                     const double* __restrict__ acc,
                                                     float* __restrict__ out) {
    double mt = 0.0, qt = 0.0;
    for (int s = threadIdx.x; s < S_TOT; s += 1024) {
        float spM = med[0 * S_TOT + s];
        float stM = med[6 * S_TOT + s];
        float dm = stM - spM;
        mt += (double)dm * (double)dm;
#pragma unroll
        for (int q = 0; q < 5; q++) {
            float sp = med[(1 + q) * S_TOT + s];
            float st = med[(7 + q) * S_TOT + s];
            float r = st / (-sp);  // f32 divide, matching reference
            qt += (double)r * (double)r;
        }
    }
#pragma unroll
    for (int off = 32; off; off >>= 1) {
        mt += __shfl_xor(mt, off, 64);
        qt += __shfl_xor(qt, off, 64);
    }
    __shared__ double smt[16], sqt[16];
    int lane = threadIdx.x & 63, w = threadIdx.x >> 6;
    if (lane == 0) { smt[w] = mt; sqt[w] = qt; }
    __syncthreads();
    if (threadIdx.x == 0) {
        double M = 0.0, Q = 0.0;
#pragma unroll
        for (int i = 0; i < 16; i++) { M += smt[i]; Q += sqt[i]; }
        double rmse = sqrt(acc[0] / ((double)T_TOT * (double)S_TOT));
        out[0] = (float)(rmse + (M + Q) / (double)S_TOT);
    }
}

// ---------------------------------------------------------------------------
extern "C" void kernel_launch(void* const* d_in, const int* in_sizes, int n_in,
                              void* d_out, int out_size, void* d_ws, size_t ws_size,
                              hipStream_t stream) {
    const float* pred = (const float*)d_in[0];
    const float* targ = (const float*)d_in[1];
    float* out = (float*)d_out;

    double* acc = (double*)d_ws;                                   // 8 B
    float* stats = (float*)((char*)d_ws + 64);                     // 12*4000*30 f32
    float* med = (float*)((char*)d_ws + 64 + (size_t)12 * S_TOT * NY * 4);  // 12*4000 f32

    zero_kernel<<<1, 1, 0, stream>>>(acc);
    stats_kernel<<<NBLK, 512, 0, stream>>>(pred, targ, stats, acc);
    theilsen_kernel<<<12 * S_TOT / 4, 256, 0, stream>>>(stats, med);
    final_kernel<<<1, 1024, 0, stream>>>(med, acc, out);
}

// Round 5
// 793.883 us; speedup vs baseline: 1.2859x; 1.2859x over previous
//
#include <hip/hip_runtime.h>
#include <cstdint>
#include <cstddef>
#include <math.h>

#define S_TOT 4000
#define NY 30
#define ND 365
#define T_TOT (NY * ND)  // 10950
#define NBLK ((S_TOT / 8) * NY)  // 15000 stats blocks

__device__ __forceinline__ float pinf() { return __uint_as_float(0x7F800000u); }

// Monotone bijection: uint key -> float (total order), inverse of
// f2key(bits) = (bits & 0x80000000) ? ~bits : (bits | 0x80000000)
__device__ inline float key2f(unsigned k) {
    unsigned bits = (k & 0x80000000u) ? (k ^ 0x80000000u) : ~k;
    return __uint_as_float(bits);
}

// count of elements <= p across the wave's R-reg value set (pads are +inf)
template <int R>
__device__ __forceinline__ int wcountR(const float (&v)[R], float p) {
    int c = 0;
#pragma unroll
    for (int i = 0; i < R; i++) c += (int)__popcll(__ballot(v[i] <= p));
    return c;
}

// Exact (need)-th smallest (1-based). Preconditions (wave-uniform):
//   count(lo) = cLo < need <= cHi = count(hi), lo < hi.
// False-position (alternating midpoint) to bracket-width <= 2, then exact
// min-extraction finisher. Bounded key-space bisection fallback keeps it
// exact for arbitrary (tie-heavy / adversarial) data.
template <int R>
__device__ float select_one(const float (&v)[R], int need,
                            float lo, int cLo, float hi, int cHi) {
    int w = cHi - cLo;
    for (int it = 0; it < 16 && w > 2; ++it) {
        float p;
        if (it & 1) {
            p = lo + 0.5f * (hi - lo);
        } else {
            float t = (float)(need - cLo) / (float)w;  // probe position only
            p = fmaf(t, hi - lo, lo);
        }
        if (!(p > lo && p < hi)) p = lo + 0.5f * (hi - lo);
        if (!(p > lo && p < hi)) return hi;  // adjacent floats: answer == hi
        int c = wcountR(v, p);
        if (c >= need) { hi = p; cHi = c; } else { lo = p; cLo = c; }
        w = cHi - cLo;
    }
    if (w > 2) {  // pathological stagnation: exact bounded bisection (rare)
        unsigned klo = 0u, khi = 0xFFFFFFFFu;
        for (int it = 0; it < 32; ++it) {
            unsigned kmid = klo + ((khi - klo) >> 1);
            if (wcountR(v, key2f(kmid)) >= need) khi = kmid; else klo = kmid + 1;
        }
        return key2f(klo);
    }
    // finisher: r-th smallest among {x > lo}, r in {1,2}
    int r = need - cLo;
    float m[R];
#pragma unroll
    for (int i = 0; i < R; i++) m[i] = (v[i] > lo) ? v[i] : pinf();
    float cur = m[0];
#pragma unroll
    for (int i = 1; i < R; i++) cur = fminf(cur, m[i]);
#pragma unroll
    for (int off = 32; off; off >>= 1) cur = fminf(cur, __shfl_xor(cur, off, 64));
    if (r == 2) {  // remove exactly one instance of cur (tie-safe), min again
        bool has = false;
#pragma unroll
        for (int i = 0; i < R; i++) has |= (m[i] == cur);
        unsigned long long bal = __ballot(has);
        int leader = __ffsll((long long)bal) - 1;
        if ((int)(threadIdx.x & 63) == leader) {
            bool done = false;
#pragma unroll
            for (int i = 0; i < R; i++) {
                if (!done && m[i] == cur) { m[i] = pinf(); done = true; }
            }
        }
        float c2 = m[0];
#pragma unroll
        for (int i = 1; i < R; i++) c2 = fminf(c2, m[i]);
#pragma unroll
        for (int off = 32; off; off >>= 1) c2 = fminf(c2, __shfl_xor(c2, off, 64));
        cur = c2;
    }
    return cur;
}

// ---------------------------------------------------------------------------
// Kernel 0: zero the f64 accumulator (no hipMemsetAsync in capture path)
// ---------------------------------------------------------------------------
__global__ void zero_kernel(double* acc) { acc[0] = 0.0; }

// ---------------------------------------------------------------------------
// Kernel 1: per-(series, year) mean + 5 exact order statistics for BOTH
// arrays, PLUS fused RMSE partial (touches every input byte exactly once).
// One wave per (series, year); block = 8 waves = 8 series x 1 year.
// Selection: moment-seeded probing (mean + z*sigma for the 4 target ranks,
// counts via ballot) -> per-rank false-position refinement -> exact finisher.
// stats layout: stats[k][s][y], k: 0=meanP, 1..5=qP (ranks 364,357,182,109,7),
//                               6=meanT, 7..11=qT
// ---------------------------------------------------------------------------
__global__ __launch_bounds__(512) void stats_kernel(const float* __restrict__ pred,
                                                    const float* __restrict__ targ,
                                                    float* __restrict__ stats,
                                                    double* __restrict__ acc) {
    const int b = blockIdx.x;
    const int work = (b & 7) * (NBLK / 8) + (b >> 3);  // XCD-contiguous remap
    const int y = work % NY;
    const int s0 = (work / NY) * 8;

    __shared__ float ldsA[ND * 9];  // [day][series(8)+pad]
    __shared__ float ldsB[ND * 9];
    __shared__ double wred[8];

    const int tid = threadIdx.x;
    const size_t base = (size_t)y * ND * S_TOT + s0;

    double rs = 0.0;  // fused RMSE partial
    for (int idx = tid; idx < ND * 8; idx += 512) {
        int d = idx >> 3, c = idx & 7;
        size_t g = base + (size_t)d * S_TOT + c;
        float pv = pred[g], tv = targ[g];
        ldsA[d * 9 + c] = pv;
        ldsB[d * 9 + c] = tv;
        float df = pv - tv;
        rs += (double)df * df;
    }
#pragma unroll
    for (int off = 32; off; off >>= 1) rs += __shfl_xor(rs, off, 64);
    const int w = tid >> 6;
    const int lane = tid & 63;
    if (lane == 0) wred[w] = rs;
    __syncthreads();  // covers LDS staging AND wred
    if (tid == 0) {
        double t = 0.0;
#pragma unroll
        for (int i = 0; i < 8; i++) t += wred[i];
        atomicAdd(acc, t);
    }

    const int s = s0 + w;
    const float PINF = pinf();

    for (int arr = 0; arr < 2; ++arr) {
        const float* lds = arr ? ldsB : ldsA;
        float v[6];
#pragma unroll
        for (int i = 0; i < 6; i++) {
            int d = i * 64 + lane;
            v[i] = (d < ND) ? lds[d * 9 + w] : PINF;  // pads sort above all data
        }
        // fused per-lane moments + min/max (pads excluded from sums/max)
        float sm = 0.f, sq = 0.f, mn = PINF, mx = -PINF;
#pragma unroll
        for (int i = 0; i < 6; i++) {
            int d = i * 64 + lane;
            float x = (d < ND) ? v[i] : 0.f;
            sm += x;
            sq = fmaf(x, x, sq);
            mn = fminf(mn, v[i]);  // +inf pads harmless
            mx = fmaxf(mx, (d < ND) ? v[i] : -PINF);
        }
#pragma unroll
        for (int off = 32; off; off >>= 1) {
            sm += __shfl_xor(sm, off, 64);
            sq += __shfl_xor(sq, off, 64);
            mn = fminf(mn, __shfl_xor(mn, off, 64));
            mx = fmaxf(mx, __shfl_xor(mx, off, 64));
        }
        const float mean = sm * (1.0f / 365.0f);
        float var = fmaxf(sq * (1.0f / 365.0f) - mean * mean, 0.f);
        float sig = sqrtf(var);
        const int cMn = wcountR(v, mn);  // tie count of the minimum (>=1)

        // Round 0: 4 ascending moment-seeded probes, shared across ranks
        const int needs[4] = {8, 110, 183, 358};            // ascending 1-based
        const float zs[4] = {-2.04f, -0.52f, 0.0f, 2.05f};  // approx normal z
        float p4[4];
        int c4[4];
        const bool seed = (sig > 0.f) && (sig < PINF) && (mean > -PINF) && (mean < PINF);
        if (seed) {
#pragma unroll
            for (int k = 0; k < 4; ++k) {
                p4[k] = fmaf(zs[k], sig, mean);
                c4[k] = wcountR(v, p4[k]);
            }
        }
        float q[4];
#pragma unroll
        for (int k = 0; k < 4; ++k) {
            const int need = needs[k];
            if (cMn >= need) { q[k] = mn; continue; }
            float lo = mn, hi = mx;
            int cLo = cMn, cHi = 365;
            if (seed) {
#pragma unroll
                for (int j = 0; j < 4; ++j) {
                    if (c4[j] < need) {
                        if (p4[j] > lo && p4[j] < hi) { lo = p4[j]; cLo = c4[j]; }
                    } else {
                        if (p4[j] < hi && p4[j] > lo) { hi = p4[j]; cHi = c4[j]; }
                    }
                }
            }
            q[k] = select_one(v, need, lo, cLo, hi, cHi);
        }

        float res[6] = {mean, mx, q[3], q[2], q[1], q[0]};  // mean,p100,p98,p50,p30,p2
        if (lane == 0) {
            const int kb = arr ? 6 : 0;
#pragma unroll
            for (int k = 0; k < 6; k++)
                stats[((size_t)(kb + k) * S_TOT + s) * NY + y] = res[k];
        }
    }
}

// ---------------------------------------------------------------------------
// Kernel 2: Theil-Sen median slope per (k, s). One wave per task.
// 435 pairwise slopes, 7/lane (pad +inf); median = rank 217 (need 218).
// Closed-form triangular decode + mean-seeded exact selection.
// ---------------------------------------------------------------------------
__global__ __launch_bounds__(256) void theilsen_kernel(const float* __restrict__ stats,
                                                       float* __restrict__ med) {
    const int task = blockIdx.x * 4 + (threadIdx.x >> 6);  // 48000 tasks
    const int lane = threadIdx.x & 63;
    const int k = task / S_TOT;
    const int s = task - k * S_TOT;
    const float* x = stats + ((size_t)k * S_TOT + s) * NY;
    const float PINF = pinf();
    float sl[7];
    float sm = 0.f, mn = PINF, mx = -PINF;
#pragma unroll
    for (int t = 0; t < 7; t++) {
        int p = t * 64 + lane;
        bool ok = (p < 435);
        int pc = ok ? p : 0;
        // row i = max i with F(i) <= p, F(i) = 29i - i(i-1)/2 (exact fixup)
        int i = (int)((59.0f - sqrtf((float)(3481 - 8 * pc))) * 0.5f);
        if (i > 28) i = 28;
        if (i < 0) i = 0;
        int Fi = 29 * i - ((i * (i - 1)) >> 1);
        if (Fi > pc) { --i; Fi = 29 * i - ((i * (i - 1)) >> 1); }
        else {
            int Fn = 29 * (i + 1) - (((i + 1) * i) >> 1);
            if (pc >= Fn) { ++i; Fi = Fn; }
        }
        int j = i + 1 + (pc - Fi);
        float slope = (x[j] - x[i]) / (float)(j - i);  // exact f32 divide
        sl[t] = ok ? slope : PINF;
        sm += ok ? slope : 0.f;
        mn = fminf(mn, sl[t]);
        mx = fmaxf(mx, ok ? slope : -PINF);
    }
#pragma unroll
    for (int off = 32; off; off >>= 1) {
        sm += __shfl_xor(sm, off, 64);
        mn = fminf(mn, __shfl_xor(mn, off, 64));
        mx = fmaxf(mx, __shfl_xor(mx, off, 64));
    }
    const int cMn = wcountR(sl, mn);
    float result;
    if (cMn >= 218) {
        result = mn;
    } else {
        float lo = mn, hi = mx;
        int cLo = cMn, cHi = 435;
        float mean = sm * (1.0f / 435.0f);
        if (mean > lo && mean < hi) {  // single seed probe at the mean
            int c0 = wcountR(sl, mean);
            if (c0 >= 218) { hi = mean; cHi = c0; } else { lo = mean; cLo = c0; }
        }
        result = select_one(sl, 218, lo, cLo, hi, cHi);
    }
    if (lane == 0) med[task] = result;
}

// ---------------------------------------------------------------------------
// Kernel 3: final combine (single block)
// ---------------------------------------------------------------------------
__global__ __launch_bounds__(1024) void final_kernel(const float* __restrict__ med,
                                                     const double* __restrict__ acc,
                                                     float* __restrict__ out) {
    double mt = 0.0, qt = 0.0;
    for (int s = threadIdx.x; s < S_TOT; s += 1024) {
        float spM = med[0 * S_TOT + s];
        float stM = med[6 * S_TOT + s];
        float dm = stM - spM;
        mt += (double)dm * (double)dm;
#pragma unroll
        for (int q = 0; q < 5; q++) {
            float sp = med[(1 + q) * S_TOT + s];
            float st = med[(7 + q) * S_TOT + s];
            float r = st / (-sp);  // f32 divide, matching reference
            qt += (double)r * (double)r;
        }
    }
#pragma unroll
    for (int off = 32; off; off >>= 1) {
        mt += __shfl_xor(mt, off, 64);
        qt += __shfl_xor(qt, off, 64);
    }
    __shared__ double smt[16], sqt[16];
    int lane = threadIdx.x & 63, w = threadIdx.x >> 6;
    if (lane == 0) { smt[w] = mt; sqt[w] = qt; }
    __syncthreads();
    if (threadIdx.x == 0) {
        double M = 0.0, Q = 0.0;
#pragma unroll
        for (int i = 0; i < 16; i++) { M += smt[i]; Q += sqt[i]; }
        double rmse = sqrt(acc[0] / ((double)T_TOT * (double)S_TOT));
        out[0] = (float)(rmse + (M + Q) / (double)S_TOT);
    }
}

// ---------------------------------------------------------------------------
extern "C" void kernel_launch(void* const* d_in, const int* in_sizes, int n_in,
                              void* d_out, int out_size, void* d_ws, size_t ws_size,
                              hipStream_t stream) {
    const float* pred = (const float*)d_in[0];
    const float* targ = (const float*)d_in[1];
    float* out = (float*)d_out;

    double* acc = (double*)d_ws;                                   // 8 B
    float* stats = (float*)((char*)d_ws + 64);                     // 12*4000*30 f32
    float* med = (float*)((char*)d_ws + 64 + (size_t)12 * S_TOT * NY * 4);  // 12*4000 f32

    zero_kernel<<<1, 1, 0, stream>>>(acc);
    stats_kernel<<<NBLK, 512, 0, stream>>>(pred, targ, stats, acc);
    theilsen_kernel<<<12 * S_TOT / 4, 256, 0, stream>>>(stats, med);
    final_kernel<<<1, 1024, 0, stream>>>(med, acc, out);
}